// Round 7
// baseline (215.678 us; speedup 1.0000x reference)
//
#include <hip/hip_runtime.h>
#include <stdint.h>
#include <stddef.h>

// Problem constants (B,S,H,D fixed by the reference)
#define B_ 2
#define H_ 16
#define S_ 2048
#define D_ 64

#define TQ 32              // q-rows per MFMA tile
#define TK 256             // k rows per resident chunk
#define NW 4               // waves per block
#define BLK (NW*64)        // 256 threads
#define NQT (S_/TQ)        // 64 q-tiles per (b,h)
#define NBLK_F (B_*H_*NQT) // fused-fallback grid

// merged-kernel role counts
#define NZ  384            // masked-rect zero blocks (12 per bh)
#define NS  1152           // sums blocks (36 per bh)
#define NWC 640            // compute-store blocks (20 per bh)
#define NTOT (NZ+NS+NWC)   // 2176

typedef __attribute__((ext_vector_type(8))) short bf16x8;
typedef __attribute__((ext_vector_type(4))) float f32x4;

// f32 -> bf16 (round-to-nearest-even)
__device__ __forceinline__ unsigned short f2bf(float f) {
  union { float f; uint32_t u; } v; v.f = f;
  uint32_t r = v.u + 0x7FFFu + ((v.u >> 16) & 1u);
  return (unsigned short)(r >> 16);
}

// stage 256-row K chunk `kc` into ldsK (bf16, XOR-swizzled 8-elem granules)
__device__ __forceinline__ void stage_k(const f32x4* kp, unsigned short* ldsK,
                                        int b, int h, int kc, int tid) {
#pragma unroll
  for (int i = 0; i < 8; ++i) {
    const int g  = i * BLK + tid;
    const int kl = g >> 3;
    const int gd = g & 7;
    const size_t gb = (((size_t)b * S_ + (kc * TK + kl)) * H_ + h) * (D_ / 4) + gd * 2;
    f32x4 v0 = kp[gb];
    f32x4 v1 = kp[gb + 1];
    bf16x8 bv;
    bv[0] = (short)f2bf(v0.x); bv[1] = (short)f2bf(v0.y);
    bv[2] = (short)f2bf(v0.z); bv[3] = (short)f2bf(v0.w);
    bv[4] = (short)f2bf(v1.x); bv[5] = (short)f2bf(v1.y);
    bv[6] = (short)f2bf(v1.z); bv[7] = (short)f2bf(v1.w);
    const int idx = (kl * D_ + gd * 8) ^ ((kl & 7) << 3);
    *reinterpret_cast<bf16x8*>(&ldsK[idx]) = bv;
  }
}

// stage 32-row Q tile into LDS (pre-scaled 1/8 = 1/sqrt(D))
__device__ __forceinline__ void stage_q(const f32x4* qp, unsigned short (*ldsQ)[72],
                                        int b, int h, int qb, int tid) {
#pragma unroll
  for (int i = 0; i < 2; ++i) {
    const int g   = i * BLK + tid;
    const int row = g >> 4;
    const int d4  = g & 15;
    f32x4 v = qp[(((size_t)b * S_ + (qb + row)) * H_ + h) * (D_ / 4) + d4];
    unsigned short* dst = &ldsQ[row][d4 * 4];
    dst[0] = f2bf(v.x * 0.125f);
    dst[1] = f2bf(v.y * 0.125f);
    dst[2] = f2bf(v.z * 0.125f);
    dst[3] = f2bf(v.w * 0.125f);
  }
}

__device__ __forceinline__ void load_qfr(const unsigned short (*ldsQ)[72],
                                         bf16x8 qfr[2][2], int colk, int rg) {
#pragma unroll
  for (int qf = 0; qf < 2; ++qf)
#pragma unroll
    for (int hh = 0; hh < 2; ++hh)
      qfr[qf][hh] = *reinterpret_cast<const bf16x8*>(&ldsQ[qf * 16 + colk][hh * 32 + rg * 8]);
}

// A-operand = K (m = k), B-operand = Q (n = q)
// D: col(lane&15) = q_local, row(rg*4+reg) = k_local
__device__ __forceinline__ void mfma_tile(const unsigned short* ldsK,
                                          const bf16x8 qfr[2][2],
                                          f32x4 acc[4][2], int w, int colk, int rg) {
#pragma unroll
  for (int kf = 0; kf < 4; ++kf) {
    const int krow = w * 64 + kf * 16 + colk;
    const int i0 = (krow * D_ + rg * 8) ^ ((krow & 7) << 3);
    const int i1 = (krow * D_ + 32 + rg * 8) ^ ((krow & 7) << 3);
    bf16x8 a0 = *reinterpret_cast<const bf16x8*>(&ldsK[i0]);
    bf16x8 a1 = *reinterpret_cast<const bf16x8*>(&ldsK[i1]);
#pragma unroll
    for (int qf = 0; qf < 2; ++qf) {
      acc[kf][qf] = __builtin_amdgcn_mfma_f32_16x16x32_bf16(a0, qfr[qf][0], acc[kf][qf], 0, 0, 0);
      acc[kf][qf] = __builtin_amdgcn_mfma_f32_16x16x32_bf16(a1, qfr[qf][1], acc[kf][qf], 0, 0, 0);
    }
  }
}

// ======================= merged producer/consumer kernel ====================
// d_ws layout: [0,4KB) control (cnt[256], ticket) -- memset to 0 per launch
//              [4KB, 4KB+2MB) wsPart partial row-sums
__global__ __launch_bounds__(BLK, 4)
void attn_merged(const float* __restrict__ Qg, const float* __restrict__ Kg,
                 int* __restrict__ ctrl, float* __restrict__ wsPart,
                 float* __restrict__ Og) {
  __shared__ alignas(16) unsigned char smem[39424];
  unsigned short* ldsK = reinterpret_cast<unsigned short*>(smem);              // 32768
  unsigned short (*ldsQ)[72] = reinterpret_cast<unsigned short (*)[72]>(smem + 32768); // 4608
  float* ldsTail = reinterpret_cast<float*>(smem + 37376);                     // 2048: S sums / W rinvL
  __shared__ int tktS;

  int* cnt    = ctrl;        // 256 counters: cnt[bh*8 + s]
  int* ticket = ctrl + 256;

  const int tid  = threadIdx.x;
  const int lane = tid & 63;
  const int w    = tid >> 6;
  const int colk = lane & 15;
  const int rg   = lane >> 4;

  if (tid == 0)
    tktS = __hip_atomic_fetch_add(ticket, 1, __ATOMIC_RELAXED, __HIP_MEMORY_SCOPE_AGENT);
  __syncthreads();
  const int t = tktS;

  const f32x4* qp = reinterpret_cast<const f32x4*>(Qg);
  const f32x4* kp = reinterpret_cast<const f32x4*>(Kg);

  if (t < NZ + NS && (t & 3) == 3) {
    // ---------------- zero role: one fully-masked 512x256 rect ----------
    const int z  = t >> 2;
    const int bh = z / 12;
    const int p  = z % 12;
    const int qg = (p < 6) ? 0 : (p < 10) ? 1 : 2;
    const int kc = (qg == 0) ? 2 + p : (qg == 1) ? p - 2 : p - 4;
    const int row0 = qg * 512, kmin = kc * TK;
    f32x4 zf = {0.f, 0.f, 0.f, 0.f};
#pragma unroll 4
    for (int it = 0; it < 128; ++it) {
      const int g = it * BLK + tid;
      const int row = row0 + (g >> 6);
      const int cg = g & 63;
      __builtin_nontemporal_store(zf, reinterpret_cast<f32x4*>(
          Og + ((size_t)bh * S_ + row) * S_ + kmin + cg * 4));
    }
    return;
  }

  if (t < NZ + NS) {
    // ---------------- S role: partial softmax denominators ---------------
    const int si = (t >> 2) * 3 + (t & 3);
    const int bh = si / 36;
    int j = si % 36;
    int kc = 0, base = 0;
    while (j >= base + (8 - kc)) { base += 8 - kc; ++kc; }
    const int ci = j - base;
    const int qt0 = kc * 8 + ci * 8;          // 8 q-tiles, rows [(kc+ci)*256,+256)
    const int b = bh >> 4, h = bh & (H_ - 1);

    stage_k(kp, ldsK, b, h, kc, tid);          // resident for whole block

    for (int i = 0; i < 8; ++i) {
      const int qb = (qt0 + i) * TQ;
      __syncthreads();                         // K ready (i==0) / ldsQ reuse
      stage_q(qp, ldsQ, b, h, qb, tid);
      __syncthreads();
      bf16x8 qfr[2][2];
      load_qfr(ldsQ, qfr, colk, rg);
      f32x4 acc[4][2];
#pragma unroll
      for (int kf = 0; kf < 4; ++kf)
#pragma unroll
        for (int qf = 0; qf < 2; ++qf) acc[kf][qf] = (f32x4)0.0f;
      mfma_tile(ldsK, qfr, acc, w, colk, rg);

      float rsum[2] = {0.f, 0.f};
#pragma unroll
      for (int kf = 0; kf < 4; ++kf)
#pragma unroll
        for (int qf = 0; qf < 2; ++qf)
#pragma unroll
          for (int r = 0; r < 4; ++r) {
            const int kk = kc * TK + w * 64 + kf * 16 + rg * 4 + r;
            const int qq = qb + qf * 16 + colk;
            rsum[qf] += (kk <= qq) ? __expf(acc[kf][qf][r]) : 0.f;
          }
#pragma unroll
      for (int qf = 0; qf < 2; ++qf) {
        float v = rsum[qf];
        v += __shfl_xor(v, 16);
        v += __shfl_xor(v, 32);
        rsum[qf] = v;
      }
      if (rg == 0) {
        ldsTail[w * 32 + colk]      = rsum[0];
        ldsTail[w * 32 + 16 + colk] = rsum[1];
      }
      __syncthreads();
      if (tid < 32) {
        const int qf = tid >> 4, ck = tid & 15;
        const float s = ldsTail[0 * 32 + qf * 16 + ck] + ldsTail[1 * 32 + qf * 16 + ck] +
                        ldsTail[2 * 32 + qf * 16 + ck] + ldsTail[3 * 32 + qf * 16 + ck];
        wsPart[((size_t)bh * 8 + kc) * S_ + qb + tid] = s;
      }
    }
    __syncthreads();                           // all wsPart stores drained (vmcnt)
    if (tid == 0)                              // release: publish this sum-class
      __hip_atomic_fetch_add(&cnt[bh * 8 + kc + ci], 1,
                             __ATOMIC_RELEASE, __HIP_MEMORY_SCOPE_AGENT);
    return;
  }

  // ---------------- W role: compute + store one 512x256 rect --------------
  {
    // heavy (16-tile) rects first, light (8-tile) last, bh-major within rank
    static const int QGt[20] = {0,1,1,1,2,2,2,2,2,3,3,3,3,3,3,3, 0,1,2,3};
    static const int KCt[20] = {0,0,1,2,0,1,2,3,4,0,1,2,3,4,5,6, 1,3,5,7};
    const int wi = t - (NZ + NS);
    const int bh = wi & 31;
    const int pr = wi >> 5;
    const int qg = QGt[pr], kc = KCt[pr];
    const int b = bh >> 4, h = bh & (H_ - 1);
    const int kmin = kc * TK;
    const int row0 = qg * 512;
    float* rinvL = ldsTail;                    // [512]

    stage_k(kp, ldsK, b, h, kc, tid);          // overlap K load with the wait

    if (tid == 0) {                            // need sum-classes 2qg, 2qg+1 done
      const int s0 = 2 * qg;
      while (__hip_atomic_load(&cnt[bh * 8 + s0], __ATOMIC_ACQUIRE,
                               __HIP_MEMORY_SCOPE_AGENT) <= s0)
        __builtin_amdgcn_s_sleep(32);
      while (__hip_atomic_load(&cnt[bh * 8 + s0 + 1], __ATOMIC_ACQUIRE,
                               __HIP_MEMORY_SCOPE_AGENT) <= s0 + 1)
        __builtin_amdgcn_s_sleep(32);
    }
    __syncthreads();                           // K staged + partials visible

    for (int lr = tid; lr < 512; lr += BLK) {  // 1/rowsum for this rect's rows
      const int q = row0 + lr;
      if (q >= kmin) {
        float s = 0.f;
        const int top = q >> 8;
        for (int c2 = 0; c2 <= top; ++c2)
          s += wsPart[((size_t)bh * 8 + c2) * S_ + q];
        rinvL[lr] = 1.0f / s;
      }
    }

    for (int i = 0; i < 16; ++i) {
      const int qb = row0 + i * TQ;
      float* outT = Og + ((size_t)bh * S_ + qb) * S_ + kmin;

      if (kmin > qb + 31) {                    // masked tile (block-uniform)
        const int rr = tid >> 3, cg = tid & 7;
        f32x4 z = {0.f, 0.f, 0.f, 0.f};
        float* rp = outT + (size_t)rr * S_;
#pragma unroll
        for (int c = 0; c < 8; ++c)
          __builtin_nontemporal_store(z, reinterpret_cast<f32x4*>(rp + (c * 8 + cg) * 4));
        continue;
      }

      __syncthreads();                         // rinvL/K ready; ldsQ reuse
      stage_q(qp, ldsQ, b, h, qb, tid);
      __syncthreads();
      bf16x8 qfr[2][2];
      load_qfr(ldsQ, qfr, colk, rg);
      f32x4 acc[4][2];
#pragma unroll
      for (int kf = 0; kf < 4; ++kf)
#pragma unroll
        for (int qf = 0; qf < 2; ++qf) acc[kf][qf] = (f32x4)0.0f;
      mfma_tile(ldsK, qfr, acc, w, colk, rg);

#pragma unroll
      for (int kf = 0; kf < 4; ++kf)
#pragma unroll
        for (int qf = 0; qf < 2; ++qf) {
          const int qq = qb + qf * 16 + colk;
          const float ri = rinvL[i * 32 + qf * 16 + colk];
          f32x4 o;
#pragma unroll
          for (int r = 0; r < 4; ++r) {
            const int kk = kmin + w * 64 + kf * 16 + rg * 4 + r;
            o[r] = (kk <= qq) ? __expf(acc[kf][qf][r]) * ri : 0.f;
          }
          __builtin_nontemporal_store(o, reinterpret_cast<f32x4*>(
              outT + (size_t)(qf * 16 + colk) * S_ + w * 64 + kf * 16 + rg * 4));
        }
    }
  }
}

// ---------------- fallback: fused two-pass (if ws too small) ---------------
__global__ __launch_bounds__(BLK, 4)
void attn_weights_fused(const float* __restrict__ Qg, const float* __restrict__ Kg,
                        float* __restrict__ Og) {
  __shared__ unsigned short ldsK[TK * D_];
  __shared__ unsigned short ldsQ[TQ][72];
  __shared__ float ldsSum[NW][2][16];

  const int tid  = threadIdx.x;
  const int lane = tid & 63;
  const int w    = tid >> 6;
  const int colk = lane & 15;
  const int rg   = lane >> 4;

  int bid = (int)blockIdx.x;
  bid = (bid & 7) * (NBLK_F / 8) + (bid >> 3);
  const int qt = bid & (NQT - 1);
  const int bh = bid >> 6;
  const int h  = bh & (H_ - 1);
  const int b  = bh >> 4;
  const int qb = qt * TQ;
  const int tmax = qb >> 8;

  float* outp = Og + ((size_t)bh * S_ + qb) * S_;
  {
    const int row = tid >> 3;
    f32x4 z = {0.f, 0.f, 0.f, 0.f};
    float* rp = outp + (size_t)row * S_;
    for (int c = (tmax + 1) * (TK / 4) + (tid & 7); c < S_ / 4; c += 8)
      *reinterpret_cast<f32x4*>(rp + c * 4) = z;
  }
  const f32x4* qp = reinterpret_cast<const f32x4*>(Qg);
  const f32x4* kp = reinterpret_cast<const f32x4*>(Kg);
  stage_q(qp, ldsQ, b, h, qb, tid);
  __syncthreads();
  bf16x8 qfr[2][2];
  load_qfr(ldsQ, qfr, colk, rg);
  float rsum[2] = {0.f, 0.f};
  for (int t = 0; t <= tmax; ++t) {
    stage_k(kp, ldsK, b, h, t, tid);
    __syncthreads();
    f32x4 acc[4][2];
#pragma unroll
    for (int kf = 0; kf < 4; ++kf)
#pragma unroll
      for (int qf = 0; qf < 2; ++qf) acc[kf][qf] = (f32x4)0.0f;
    mfma_tile(ldsK, qfr, acc, w, colk, rg);
#pragma unroll
    for (int kf = 0; kf < 4; ++kf)
#pragma unroll
      for (int qf = 0; qf < 2; ++qf)
#pragma unroll
        for (int r = 0; r < 4; ++r) {
          const int kk = t * TK + w * 64 + kf * 16 + rg * 4 + r;
          const int qq = qb + qf * 16 + colk;
          rsum[qf] += (kk <= qq) ? __expf(acc[kf][qf][r]) : 0.f;
        }
    __syncthreads();
  }
#pragma unroll
  for (int qf = 0; qf < 2; ++qf) {
    float v = rsum[qf];
    v += __shfl_xor(v, 16);
    v += __shfl_xor(v, 32);
    rsum[qf] = v;
  }
  if (rg == 0) { ldsSum[w][0][colk] = rsum[0]; ldsSum[w][1][colk] = rsum[1]; }
  __syncthreads();
  float rinv[2];
#pragma unroll
  for (int qf = 0; qf < 2; ++qf)
    rinv[qf] = 1.0f / (ldsSum[0][qf][colk] + ldsSum[1][qf][colk] +
                       ldsSum[2][qf][colk] + ldsSum[3][qf][colk]);
  for (int t = 0; t <= tmax; ++t) {
    stage_k(kp, ldsK, b, h, t, tid);
    __syncthreads();
    f32x4 acc[4][2];
#pragma unroll
    for (int kf = 0; kf < 4; ++kf)
#pragma unroll
      for (int qf = 0; qf < 2; ++qf) acc[kf][qf] = (f32x4)0.0f;
    mfma_tile(ldsK, qfr, acc, w, colk, rg);
#pragma unroll
    for (int kf = 0; kf < 4; ++kf)
#pragma unroll
      for (int qf = 0; qf < 2; ++qf) {
        f32x4 o;
#pragma unroll
        for (int r = 0; r < 4; ++r) {
          const int kk = t * TK + w * 64 + kf * 16 + rg * 4 + r;
          const int qq = qb + qf * 16 + colk;
          o[r] = (kk <= qq) ? __expf(acc[kf][qf][r]) * rinv[qf] : 0.f;
        }
        *reinterpret_cast<f32x4*>(outp + (size_t)(qf * 16 + colk) * S_ +
                                  t * TK + w * 64 + kf * 16 + rg * 4) = o;
      }
    __syncthreads();
  }
}

extern "C" void kernel_launch(void* const* d_in, const int* in_sizes, int n_in,
                              void* d_out, int out_size, void* d_ws, size_t ws_size,
                              hipStream_t stream) {
  const float* Qg = (const float*)d_in[0];
  const float* Kg = (const float*)d_in[1];
  // d_in[2] is the causal mask; tril by construction -> k<=q predicate
  float* Og = (float*)d_out;
  const size_t need = 4096 + (size_t)32 * 8 * S_ * sizeof(float);  // ctrl + 2MB
  if (ws_size >= need) {
    int* ctrl = (int*)d_ws;
    float* wsPart = (float*)((char*)d_ws + 4096);
    hipMemsetAsync(d_ws, 0, 4096, stream);     // reset counters+ticket each call
    attn_merged<<<dim3(NTOT), dim3(BLK), 0, stream>>>(Qg, Kg, ctrl, wsPart, Og);
  } else {
    attn_weights_fused<<<dim3(NBLK_F), dim3(BLK), 0, stream>>>(Qg, Kg, Og);
  }
}

// Round 8
// 154.276 us; speedup vs baseline: 1.3980x; 1.3980x over previous
//
#include <hip/hip_runtime.h>
#include <stdint.h>
#include <stddef.h>

// Problem constants (B,S,H,D fixed by the reference)
#define B_ 2
#define H_ 16
#define S_ 2048
#define D_ 64

#define TQ 32              // q-rows per MFMA tile
#define TK 256             // k rows per resident chunk
#define NW 4               // waves per block
#define BLK (NW*64)        // 256 threads
#define NQT (S_/TQ)        // 64 q-tiles per (b,h)
#define NBLK_F (B_*H_*NQT) // fused-fallback grid
#define NBLK_S (32*36)     // sums grid: 32 bh x sum_kc(8-kc)=36
#define NBLK_W (32*8*4)    // store grid: bh x kc x qg

typedef __attribute__((ext_vector_type(8))) short bf16x8;
typedef __attribute__((ext_vector_type(4))) float f32x4;

// f32 -> bf16 (round-to-nearest-even)
__device__ __forceinline__ unsigned short f2bf(float f) {
  union { float f; uint32_t u; } v; v.f = f;
  uint32_t r = v.u + 0x7FFFu + ((v.u >> 16) & 1u);
  return (unsigned short)(r >> 16);
}

// stage 256-row K chunk `kc` into ldsK (bf16, XOR-swizzled 8-elem granules)
__device__ __forceinline__ void stage_k(const f32x4* kp, unsigned short* ldsK,
                                        int b, int h, int kc, int tid) {
#pragma unroll
  for (int i = 0; i < 8; ++i) {
    const int g  = i * BLK + tid;
    const int kl = g >> 3;
    const int gd = g & 7;
    const size_t gb = (((size_t)b * S_ + (kc * TK + kl)) * H_ + h) * (D_ / 4) + gd * 2;
    f32x4 v0 = kp[gb];
    f32x4 v1 = kp[gb + 1];
    bf16x8 bv;
    bv[0] = (short)f2bf(v0.x); bv[1] = (short)f2bf(v0.y);
    bv[2] = (short)f2bf(v0.z); bv[3] = (short)f2bf(v0.w);
    bv[4] = (short)f2bf(v1.x); bv[5] = (short)f2bf(v1.y);
    bv[6] = (short)f2bf(v1.z); bv[7] = (short)f2bf(v1.w);
    const int idx = (kl * D_ + gd * 8) ^ ((kl & 7) << 3);
    *reinterpret_cast<bf16x8*>(&ldsK[idx]) = bv;
  }
}

// stage 32-row Q tile into LDS (pre-scaled 1/8 = 1/sqrt(D))
__device__ __forceinline__ void stage_q(const f32x4* qp, unsigned short (*ldsQ)[72],
                                        int b, int h, int qb, int tid) {
#pragma unroll
  for (int i = 0; i < 2; ++i) {
    const int g   = i * BLK + tid;
    const int row = g >> 4;
    const int d4  = g & 15;
    f32x4 v = qp[(((size_t)b * S_ + (qb + row)) * H_ + h) * (D_ / 4) + d4];
    unsigned short* dst = &ldsQ[row][d4 * 4];
    dst[0] = f2bf(v.x * 0.125f);
    dst[1] = f2bf(v.y * 0.125f);
    dst[2] = f2bf(v.z * 0.125f);
    dst[3] = f2bf(v.w * 0.125f);
  }
}

// T14 split staging: issue global loads early...
struct QPre { f32x4 a, b; };
__device__ __forceinline__ QPre qpre_load(const f32x4* qp, int b, int h, int qb, int tid) {
  QPre r;
  {
    const int g = tid;            // half 0
    r.a = qp[(((size_t)b * S_ + (qb + (g >> 4))) * H_ + h) * (D_ / 4) + (g & 15)];
  }
  {
    const int g = BLK + tid;      // half 1
    r.b = qp[(((size_t)b * S_ + (qb + (g >> 4))) * H_ + h) * (D_ / 4) + (g & 15)];
  }
  return r;
}
// ...convert + LDS-write late (after the barrier)
__device__ __forceinline__ void qpre_write(unsigned short (*ldsQ)[72], const QPre& p, int tid) {
#pragma unroll
  for (int i = 0; i < 2; ++i) {
    const int g   = i * BLK + tid;
    const int row = g >> 4;
    const int d4  = g & 15;
    const f32x4 v = i ? p.b : p.a;
    unsigned short* dst = &ldsQ[row][d4 * 4];
    dst[0] = f2bf(v.x * 0.125f);
    dst[1] = f2bf(v.y * 0.125f);
    dst[2] = f2bf(v.z * 0.125f);
    dst[3] = f2bf(v.w * 0.125f);
  }
}

__device__ __forceinline__ void load_qfr(const unsigned short (*ldsQ)[72],
                                         bf16x8 qfr[2][2], int colk, int rg) {
#pragma unroll
  for (int qf = 0; qf < 2; ++qf)
#pragma unroll
    for (int hh = 0; hh < 2; ++hh)
      qfr[qf][hh] = *reinterpret_cast<const bf16x8*>(&ldsQ[qf * 16 + colk][hh * 32 + rg * 8]);
}

// A-operand = K (m = k), B-operand = Q (n = q)
// D: col(lane&15) = q_local, row(rg*4+reg) = k_local
__device__ __forceinline__ void mfma_tile(const unsigned short* ldsK,
                                          const bf16x8 qfr[2][2],
                                          f32x4 acc[4][2], int w, int colk, int rg) {
#pragma unroll
  for (int kf = 0; kf < 4; ++kf) {
    const int krow = w * 64 + kf * 16 + colk;
    const int i0 = (krow * D_ + rg * 8) ^ ((krow & 7) << 3);
    const int i1 = (krow * D_ + 32 + rg * 8) ^ ((krow & 7) << 3);
    bf16x8 a0 = *reinterpret_cast<const bf16x8*>(&ldsK[i0]);
    bf16x8 a1 = *reinterpret_cast<const bf16x8*>(&ldsK[i1]);
#pragma unroll
    for (int qf = 0; qf < 2; ++qf) {
      acc[kf][qf] = __builtin_amdgcn_mfma_f32_16x16x32_bf16(a0, qfr[qf][0], acc[kf][qf], 0, 0, 0);
      acc[kf][qf] = __builtin_amdgcn_mfma_f32_16x16x32_bf16(a1, qfr[qf][1], acc[kf][qf], 0, 0, 0);
    }
  }
}

// ---------------- kernel S: per-(kc,row) partial softmax denominators ------
// (byte-identical behavior to R4's proven attn_sums_v4)
__global__ __launch_bounds__(BLK, 4)
void attn_sums_v4(const float* __restrict__ Qg, const float* __restrict__ Kg,
                  float* __restrict__ wsPart) {
  __shared__ unsigned short ldsK[TK * D_];
  __shared__ unsigned short ldsQ[TQ][72];
  __shared__ float ldsSum[NW][2][16];

  const int tid  = threadIdx.x;
  const int lane = tid & 63;
  const int w    = tid >> 6;
  const int colk = lane & 15;
  const int rg   = lane >> 4;

  int bid = (int)blockIdx.x;
  bid = (bid & 7) * (NBLK_S / 8) + (bid >> 3);     // bijective XCD swizzle
  const int bh = bid / 36;
  int j = bid - bh * 36;
  int kc = 0, base = 0;
  while (j >= base + (8 - kc)) { base += 8 - kc; ++kc; }
  const int ci = j - base;
  const int qt0 = kc * 8 + ci * 8;
  const int b = bh >> 4, h = bh & (H_ - 1);

  const f32x4* qp = reinterpret_cast<const f32x4*>(Qg);
  const f32x4* kp = reinterpret_cast<const f32x4*>(Kg);

  stage_k(kp, ldsK, b, h, kc, tid);

  for (int i = 0; i < 8; ++i) {
    const int qt = qt0 + i;
    const int qb = qt * TQ;
    __syncthreads();
    stage_q(qp, ldsQ, b, h, qb, tid);
    __syncthreads();
    bf16x8 qfr[2][2];
    load_qfr(ldsQ, qfr, colk, rg);
    f32x4 acc[4][2];
#pragma unroll
    for (int kf = 0; kf < 4; ++kf)
#pragma unroll
      for (int qf = 0; qf < 2; ++qf) acc[kf][qf] = (f32x4)0.0f;
    mfma_tile(ldsK, qfr, acc, w, colk, rg);

    float rsum[2] = {0.f, 0.f};
#pragma unroll
    for (int kf = 0; kf < 4; ++kf)
#pragma unroll
      for (int qf = 0; qf < 2; ++qf)
#pragma unroll
        for (int r = 0; r < 4; ++r) {
          const int kk = kc * TK + w * 64 + kf * 16 + rg * 4 + r;
          const int qq = qb + qf * 16 + colk;
          rsum[qf] += (kk <= qq) ? __expf(acc[kf][qf][r]) : 0.f;
        }
#pragma unroll
    for (int qf = 0; qf < 2; ++qf) {
      float v = rsum[qf];
      v += __shfl_xor(v, 16);
      v += __shfl_xor(v, 32);
      rsum[qf] = v;
    }
    if (rg == 0) { ldsSum[w][0][colk] = rsum[0]; ldsSum[w][1][colk] = rsum[1]; }
    __syncthreads();
    if (tid < 32) {
      const int qf = tid >> 4, ck = tid & 15;
      const float s = ldsSum[0][qf][ck] + ldsSum[1][qf][ck] +
                      ldsSum[2][qf][ck] + ldsSum[3][qf][ck];
      wsPart[((size_t)bh * 8 + kc) * S_ + qb + tid] = s;
    }
  }
}

// ---------------- kernel W v6: drain-free store loop -----------------------
// R4 decomposition and math, but the 16-tile loop uses raw s_barrier with
// lgkmcnt-only waits (stores NEVER drained mid-loop) + T14 reg-prefetched Q.
__global__ __launch_bounds__(BLK, 4)
void attn_store_v6(const float* __restrict__ Qg, const float* __restrict__ Kg,
                   const float* __restrict__ wsPart, float* __restrict__ Og) {
  __shared__ unsigned short ldsK[TK * D_];   // 32 KB
  __shared__ unsigned short ldsQ[TQ][72];    // 4.5 KB (single buffer)
  __shared__ float rinvL[512];               // 2 KB   -> 39424 B, 4 blocks/CU

  const int tid  = threadIdx.x;
  const int lane = tid & 63;
  const int w    = tid >> 6;
  const int colk = lane & 15;
  const int rg   = lane >> 4;

  int bid = (int)blockIdx.x;
  bid = (bid & 7) * (NBLK_W / 8) + (bid >> 3);     // bijective XCD swizzle
  const int bh = bid >> 5;
  const int r5 = bid & 31;
  const int kc = r5 >> 2;
  const int qg = r5 & 3;
  const int b = bh >> 4, h = bh & (H_ - 1);
  const int kmin = kc * TK;
  const int row0 = qg * 512;

  // fully-masked rectangle: stream zeros (nt), exit
  if (kmin > row0 + 511) {
    f32x4 z = {0.f, 0.f, 0.f, 0.f};
#pragma unroll 4
    for (int it = 0; it < 128; ++it) {
      const int g = it * BLK + tid;
      const int row = row0 + (g >> 6);
      const int cg = g & 63;
      __builtin_nontemporal_store(z, reinterpret_cast<f32x4*>(
          Og + ((size_t)bh * S_ + row) * S_ + kmin + cg * 4));
    }
    return;
  }

  const f32x4* qp = reinterpret_cast<const f32x4*>(Qg);
  const f32x4* kp = reinterpret_cast<const f32x4*>(Kg);

  // first unmasked tile index: kmin-row0 is 0 or 256 here -> i0 in {0, 8}
  const int i0 = (kmin > row0) ? ((kmin - row0) >> 5) : 0;

  // masked tile prefix: zero-fill now (overlaps the K-stage reads below)
  if (i0 > 0) {
    f32x4 z = {0.f, 0.f, 0.f, 0.f};
#pragma unroll 4
    for (int it = 0; it < 64; ++it) {              // 256 rows x 256 cols
      const int g = it * BLK + tid;
      const int row = row0 + (g >> 6);
      const int cg = g & 63;
      __builtin_nontemporal_store(z, reinterpret_cast<f32x4*>(
          Og + ((size_t)bh * S_ + row) * S_ + kmin + cg * 4));
    }
  }

  stage_k(kp, ldsK, b, h, kc, tid);

  // 1/rowsum for this block's 512 rows (only rows >= kmin read later)
  for (int lr = tid; lr < 512; lr += BLK) {
    const int q = row0 + lr;
    if (q >= kmin) {
      float s = 0.f;
      const int top = q >> 8;
      for (int c2 = 0; c2 <= top; ++c2)
        s += wsPart[((size_t)bh * 8 + c2) * S_ + q];
      rinvL[lr] = 1.0f / s;
    }
  }

  stage_q(qp, ldsQ, b, h, row0 + i0 * TQ, tid);    // tile i0 into LDS
  __syncthreads();                                 // ONE full drain (prologue)

  // prefetch tile i0+1 into registers (issued, consumed next iteration)
  QPre pre;
  if (i0 + 1 < 16) pre = qpre_load(qp, b, h, row0 + (i0 + 1) * TQ, tid);

  for (int i = i0; i < 16; ++i) {
    const int qb = row0 + i * TQ;
    float* outT = Og + ((size_t)bh * S_ + qb) * S_ + kmin;

    bf16x8 qfr[2][2];
    load_qfr(ldsQ, qfr, colk, rg);                 // ds_read_b128 x4
    asm volatile("s_waitcnt lgkmcnt(0)" ::: "memory");  // my reads complete
    __builtin_amdgcn_sched_barrier(0);
    __builtin_amdgcn_s_barrier();                  // all waves' reads done

    if (i + 1 < 16) {
      qpre_write(ldsQ, pre, tid);                  // tile i+1 -> LDS (late write)
      if (i + 2 < 16) pre = qpre_load(qp, b, h, row0 + (i + 2) * TQ, tid);
      asm volatile("s_waitcnt lgkmcnt(0)" ::: "memory");  // my ds_writes done
    }
    __builtin_amdgcn_s_barrier();                  // buf ready for next iter

    f32x4 acc[4][2];
#pragma unroll
    for (int kf = 0; kf < 4; ++kf)
#pragma unroll
      for (int qf = 0; qf < 2; ++qf) acc[kf][qf] = (f32x4)0.0f;
    mfma_tile(ldsK, qfr, acc, w, colk, rg);

#pragma unroll
    for (int kf = 0; kf < 4; ++kf)
#pragma unroll
      for (int qf = 0; qf < 2; ++qf) {
        const int qq = qb + qf * 16 + colk;
        const float ri = rinvL[i * 32 + qf * 16 + colk];
        f32x4 o;
#pragma unroll
        for (int r = 0; r < 4; ++r) {
          const int kk = kmin + w * 64 + kf * 16 + rg * 4 + r;
          o[r] = (kk <= qq) ? __expf(acc[kf][qf][r]) * ri : 0.f;
        }
        __builtin_nontemporal_store(o, reinterpret_cast<f32x4*>(
            outT + (size_t)(qf * 16 + colk) * S_ + w * 64 + kf * 16 + rg * 4));
      }
    // NOTE: no vmcnt drain — stores stay in flight across iterations
  }
}

// ---------------- fallback: fused two-pass (if ws too small) ---------------
__global__ __launch_bounds__(BLK, 4)
void attn_weights_fused(const float* __restrict__ Qg, const float* __restrict__ Kg,
                        float* __restrict__ Og) {
  __shared__ unsigned short ldsK[TK * D_];
  __shared__ unsigned short ldsQ[TQ][72];
  __shared__ float ldsSum[NW][2][16];

  const int tid  = threadIdx.x;
  const int lane = tid & 63;
  const int w    = tid >> 6;
  const int colk = lane & 15;
  const int rg   = lane >> 4;

  int bid = (int)blockIdx.x;
  bid = (bid & 7) * (NBLK_F / 8) + (bid >> 3);
  const int qt = bid & (NQT - 1);
  const int bh = bid >> 6;
  const int h  = bh & (H_ - 1);
  const int b  = bh >> 4;
  const int qb = qt * TQ;
  const int tmax = qb >> 8;

  float* outp = Og + ((size_t)bh * S_ + qb) * S_;
  {
    const int row = tid >> 3;
    f32x4 z = {0.f, 0.f, 0.f, 0.f};
    float* rp = outp + (size_t)row * S_;
    for (int c = (tmax + 1) * (TK / 4) + (tid & 7); c < S_ / 4; c += 8)
      *reinterpret_cast<f32x4*>(rp + c * 4) = z;
  }
  const f32x4* qp = reinterpret_cast<const f32x4*>(Qg);
  const f32x4* kp = reinterpret_cast<const f32x4*>(Kg);
  stage_q(qp, ldsQ, b, h, qb, tid);
  __syncthreads();
  bf16x8 qfr[2][2];
  load_qfr(ldsQ, qfr, colk, rg);
  float rsum[2] = {0.f, 0.f};
  for (int t = 0; t <= tmax; ++t) {
    stage_k(kp, ldsK, b, h, t, tid);
    __syncthreads();
    f32x4 acc[4][2];
#pragma unroll
    for (int kf = 0; kf < 4; ++kf)
#pragma unroll
      for (int qf = 0; qf < 2; ++qf) acc[kf][qf] = (f32x4)0.0f;
    mfma_tile(ldsK, qfr, acc, w, colk, rg);
#pragma unroll
    for (int kf = 0; kf < 4; ++kf)
#pragma unroll
      for (int qf = 0; qf < 2; ++qf)
#pragma unroll
        for (int r = 0; r < 4; ++r) {
          const int kk = t * TK + w * 64 + kf * 16 + rg * 4 + r;
          const int qq = qb + qf * 16 + colk;
          rsum[qf] += (kk <= qq) ? __expf(acc[kf][qf][r]) : 0.f;
        }
    __syncthreads();
  }
#pragma unroll
  for (int qf = 0; qf < 2; ++qf) {
    float v = rsum[qf];
    v += __shfl_xor(v, 16);
    v += __shfl_xor(v, 32);
    rsum[qf] = v;
  }
  if (rg == 0) { ldsSum[w][0][colk] = rsum[0]; ldsSum[w][1][colk] = rsum[1]; }
  __syncthreads();
  float rinv[2];
#pragma unroll
  for (int qf = 0; qf < 2; ++qf)
    rinv[qf] = 1.0f / (ldsSum[0][qf][colk] + ldsSum[1][qf][colk] +
                       ldsSum[2][qf][colk] + ldsSum[3][qf][colk]);
  for (int t = 0; t <= tmax; ++t) {
    stage_k(kp, ldsK, b, h, t, tid);
    __syncthreads();
    f32x4 acc[4][2];
#pragma unroll
    for (int kf = 0; kf < 4; ++kf)
#pragma unroll
      for (int qf = 0; qf < 2; ++qf) acc[kf][qf] = (f32x4)0.0f;
    mfma_tile(ldsK, qfr, acc, w, colk, rg);
#pragma unroll
    for (int kf = 0; kf < 4; ++kf)
#pragma unroll
      for (int qf = 0; qf < 2; ++qf) {
        f32x4 o;
#pragma unroll
        for (int r = 0; r < 4; ++r) {
          const int kk = t * TK + w * 64 + kf * 16 + rg * 4 + r;
          const int qq = qb + qf * 16 + colk;
          o[r] = (kk <= qq) ? __expf(acc[kf][qf][r]) * rinv[qf] : 0.f;
        }
        *reinterpret_cast<f32x4*>(outp + (size_t)(qf * 16 + colk) * S_ +
                                  t * TK + w * 64 + kf * 16 + rg * 4) = o;
      }
    __syncthreads();
  }
}

extern "C" void kernel_launch(void* const* d_in, const int* in_sizes, int n_in,
                              void* d_out, int out_size, void* d_ws, size_t ws_size,
                              hipStream_t stream) {
  const float* Qg = (const float*)d_in[0];
  const float* Kg = (const float*)d_in[1];
  // d_in[2] is the causal mask; tril by construction -> k<=q predicate
  float* Og = (float*)d_out;
  const size_t need = (size_t)32 * 8 * S_ * sizeof(float);   // 2 MB partials
  if (ws_size >= need) {
    float* wsPart = (float*)d_ws;
    attn_sums_v4 <<<dim3(NBLK_S), dim3(BLK), 0, stream>>>(Qg, Kg, wsPart);
    attn_store_v6<<<dim3(NBLK_W), dim3(BLK), 0, stream>>>(Qg, Kg, wsPart, Og);
  } else {
    attn_weights_fused<<<dim3(NBLK_F), dim3(BLK), 0, stream>>>(Qg, Kg, Og);
  }
}